// Round 13
// baseline (82.378 us; speedup 1.0000x reference)
//
#include <hip/hip_runtime.h>

typedef _Float16 f16x8 __attribute__((ext_vector_type(8)));
typedef __fp16 fp16x2 __attribute__((ext_vector_type(2)));
typedef float f32x4 __attribute__((ext_vector_type(4)));

#define NTHR 256
constexpr float EPS = 1e-5f;
constexpr int NBLOCKS = 4096;   // 4096 x 256 rows

// ---- ws byte offsets ----
// fc1 k-slots are PERMUTED: slot 16h+4g+i (h<2,g<4,i<4) holds feature 8g+4h+i;
// slots 32..35 -> features 32..35; slot 36 -> bias (const-1 feature); rest 0.
// So B-frag lane-group gq supplies contiguous features 8gq..8gq+7.
#define TAB_B   0       // f16 [29][10]  embedding-MLP table, stride 10 (580 B)
#define W1_B    1024    // f16 [48][64]  fc1 (bn1+cbn folded, permuted, bias slot 36)
#define W2_B    7168    // f16 [32][64]  fc2 (bn2 folded, bias at k=36)
#define W3_B    11264   // f16 [16][32]  fc3 (bn3 folded, bias at k=18)
#define W4_B    12736   // f32 [16]  fc4 delta row (w 0..8, bias at 9)

__device__ __forceinline__ ushort f16bits(float x) {
    union { _Float16 h; ushort u; } c; c.h = (_Float16)x; return c.u;
}
__device__ __forceinline__ uint pk2(float a, float b) {
    union { fp16x2 h; uint u; } c; c.h = __builtin_amdgcn_cvt_pkrtz(a, b); return c.u;
}
__device__ __forceinline__ uint pkrelu(float a, float b) {
    return pk2(fmaxf(a, 0.f), fmaxf(b, 0.f));
}
__device__ __forceinline__ f16x8 mk8(uint a, uint b, uint c, uint d) {
    union { uint u[4]; f16x8 v; } f;
    f.u[0] = a; f.u[1] = b; f.u[2] = c; f.u[3] = d;
    return f.v;
}
__device__ __forceinline__ f16x8 ldw_frag(const ushort* wp, int m, int stride, int kb, int g) {
    const ushort* p = wp + m * stride + kb + 4 * g;
    uint2 lo = *(const uint2*)p;
    uint2 hi = *(const uint2*)(p + 16);
    return mk8(lo.x, lo.y, hi.x, hi.y);
}

__global__ __launch_bounds__(NTHR) void prep_kernel(
    const float* __restrict__ embt, const float* __restrict__ w1,
    const float* __restrict__ b1,   const float* __restrict__ w2,
    const float* __restrict__ b2,
    const float* __restrict__ cbn_g, const float* __restrict__ cbn_b,
    const float* __restrict__ cbn_m, const float* __restrict__ cbn_v,
    const float* __restrict__ f1w, const float* __restrict__ f1b,
    const float* __restrict__ f2w, const float* __restrict__ f2b,
    const float* __restrict__ f3w, const float* __restrict__ f3b,
    const float* __restrict__ f4w, const float* __restrict__ f4b,
    const float* __restrict__ bn1g, const float* __restrict__ bn1b,
    const float* __restrict__ bn1m, const float* __restrict__ bn1v,
    const float* __restrict__ bn2g, const float* __restrict__ bn2b,
    const float* __restrict__ bn2m, const float* __restrict__ bn2v,
    const float* __restrict__ bn3g, const float* __restrict__ bn3b,
    const float* __restrict__ bn3m, const float* __restrict__ bn3v,
    char* __restrict__ ws)
{
    const int t = threadIdx.x;
    ushort* tab = (ushort*)(ws + TAB_B);
    ushort* w1o = (ushort*)(ws + W1_B);
    ushort* w2o = (ushort*)(ws + W2_B);
    ushort* w3o = (ushort*)(ws + W3_B);
    float* w4o = (float*)(ws + W4_B);

    // embedding-MLP table [29][10] f16 (cols 5..9 zero — stride 10 breaks LDS
    // bank aliasing between the 4 lane-groups, whose j's differ by 8)
    for (int i = t; i < 290; i += NTHR) {
        int j = i / 10, c = i % 10;
        float xe = 0.f;
        if (c < 5) {
            xe = b2[j];
            for (int e = 0; e < 6; e++) {
                float a = b1[j * 6 + e];
                for (int d = 0; d < 6; d++)
                    a += embt[(j * 5 + c) * 6 + d] * w1[j * 36 + d * 6 + e];
                xe += fmaxf(a, 0.f) * w2[j * 6 + e];
            }
        }
        tab[i] = f16bits(xe);
    }
    // fc1 [48][64] with k-slot permutation
    for (int i = t; i < 3072; i += NTHR) {
        int n = i / 64, k = i % 64;
        int feat = (k < 32) ? (8 * ((k >> 2) & 3) + 4 * (k >> 4) + (k & 3)) : k;
        float v = 0.f;
        if (n < 36) {
            float s1 = bn1g[n] * rsqrtf(bn1v[n] + EPS);
            if (feat < 36) {
                v = f1w[n * 36 + feat] * s1;
                if (feat < 7) v *= cbn_g[feat] * rsqrtf(cbn_v[feat] + EPS);
            } else if (feat == 36) {
                v = f1b[n] * s1 + bn1b[n] - bn1m[n] * s1;
                for (int kk = 0; kk < 7; kk++) {
                    float cs = cbn_g[kk] * rsqrtf(cbn_v[kk] + EPS);
                    float ct = cbn_b[kk] - cbn_m[kk] * cs;
                    v += f1w[n * 36 + kk] * s1 * ct;
                }
            }
        } else if (n == 36 && k == 36) {
            v = 1.f;
        }
        w1o[i] = f16bits(v);
    }
    // fc2 [32][64] (unchanged: k = h1 feature; bias at k=36; identity row 18)
    for (int i = t; i < 2048; i += NTHR) {
        int n = i / 64, k = i % 64;
        float v = 0.f;
        if (n < 18) {
            float s = bn2g[n] * rsqrtf(bn2v[n] + EPS);
            if (k < 36) v = f2w[n * 36 + k] * s;
            else if (k == 36) v = f2b[n] * s + bn2b[n] - bn2m[n] * s;
        } else if (n == 18 && k == 36) {
            v = 1.f;
        }
        w2o[i] = f16bits(v);
    }
    // fc3 [16][32]
    for (int i = t; i < 512; i += NTHR) {
        int n = i / 32, k = i % 32;
        float v = 0.f;
        if (n < 9) {
            float s = bn3g[n] * rsqrtf(bn3v[n] + EPS);
            if (k < 18) v = f3w[n * 18 + k] * s;
            else if (k == 18) v = f3b[n] * s + bn3b[n] - bn3m[n] * s;
        } else if (n == 9 && k == 18) {
            v = 1.f;
        }
        w3o[i] = f16bits(v);
    }
    if (t < 16) w4o[t] = (t < 9) ? (f4w[9 + t] - f4w[t]) : (t == 9 ? (f4b[1] - f4b[0]) : 0.f);
}

__global__ __launch_bounds__(NTHR, 5) void recovery_net_kernel(
    const float* __restrict__ xcon, const int* __restrict__ xcat,
    const char* __restrict__ ws, float2* __restrict__ out)
{
    __shared__ ushort s_tab[4][292];   // per-wave table replica — ONLY LDS (2336 B)

    const int t = threadIdx.x;
    const int lane = t & 63, w = t >> 6;
    const int l15 = lane & 15, gq = lane >> 4;
    const int bRow = blockIdx.x * 256 + w * 64;

    // stage per-wave table replica (580 B = 145 dwords)
    for (int idx = lane; idx < 145; idx += 64)
        ((uint*)s_tab[w])[idx] = ((const uint*)(ws + TAB_B))[idx];

    // resident fc1 weights + fc4 row (issued while tab staging is in flight)
    const ushort* w1p = (const ushort*)(ws + W1_B);
    const ushort* w2p = (const ushort*)(ws + W2_B);
    const ushort* w3p = (const ushort*)(ws + W3_B);
    f16x8 a1[3][2];
#pragma unroll
    for (int mt = 0; mt < 3; mt++) {
        a1[mt][0] = ldw_frag(w1p, mt * 16 + l15, 64, 0, gq);
        a1[mt][1] = ldw_frag(w1p, mt * 16 + l15, 64, 32, gq);
    }
    const float4 w4v = *(const float4*)((const float*)(ws + W4_B) + 4 * gq);

    asm volatile("s_waitcnt lgkmcnt(0)" ::: "memory");
    __builtin_amdgcn_wave_barrier();
    const ushort* tb = s_tab[w];

    // ---- 4 batch tiles of 16 rows; B-fragments built straight from global ----
#pragma unroll
    for (int bt = 0; bt < 4; bt++) {
        const int r = bRow + 16 * bt + l15;
        const int* kp = xcat + (size_t)r * 29;
        uint u0, u1, u2, u3, cw0 = 0, cw1 = 0;
        if (gq == 0) {
            // features 0..7 = xcon[0..6] + cat0; plus features 32..35 = cats 25..28
            const float* cp = xcon + (size_t)r * 7;
            float f0 = cp[0], f1 = cp[1], f2 = cp[2], f3 = cp[3];
            float f4 = cp[4], f5 = cp[5], f6 = cp[6];
            int m7 = kp[0], e0 = kp[25], e1 = kp[26], e2 = kp[27], e3 = kp[28];
            u0 = pk2(f0, f1);
            u1 = pk2(f2, f3);
            u2 = pk2(f4, f5);
            u3 = (uint)f16bits(f6) | ((uint)tb[m7] << 16);
            cw0 = (uint)tb[250 + e0] | ((uint)tb[260 + e1] << 16);
            cw1 = (uint)tb[270 + e2] | ((uint)tb[280 + e3] << 16);
        } else {
            // features 8gq..8gq+7 = cats jb..jb+7, jb = 8gq-7
            const int jb = 8 * gq - 7;
            const int* bp = kp + jb;
            int m0 = bp[0], m1 = bp[1], m2 = bp[2], m3 = bp[3];
            int m4 = bp[4], m5 = bp[5], m6 = bp[6], m7 = bp[7];
            const ushort* tj = tb + jb * 10;
            u0 = (uint)tj[m0] | ((uint)tj[10 + m1] << 16);
            u1 = (uint)tj[20 + m2] | ((uint)tj[30 + m3] << 16);
            u2 = (uint)tj[40 + m4] | ((uint)tj[50 + m5] << 16);
            u3 = (uint)tj[60 + m6] | ((uint)tj[70 + m7] << 16);
            cw0 = (gq == 1) ? 0x00003C00u : 0u;   // const-1 feature at slot 36
        }
        f16x8 xb0 = mk8(u0, u1, u2, u3);
        f16x8 xb1 = mk8(cw0, cw1, 0u, 0u);

        // fc1 (bias via slot 36)
        f32x4 c10 = {0.f, 0.f, 0.f, 0.f};
        f32x4 c11 = {0.f, 0.f, 0.f, 0.f};
        f32x4 c12 = {0.f, 0.f, 0.f, 0.f};
        c10 = __builtin_amdgcn_mfma_f32_16x16x32_f16(a1[0][0], xb0, c10, 0, 0, 0);
        c11 = __builtin_amdgcn_mfma_f32_16x16x32_f16(a1[1][0], xb0, c11, 0, 0, 0);
        c12 = __builtin_amdgcn_mfma_f32_16x16x32_f16(a1[2][0], xb0, c12, 0, 0, 0);
        c10 = __builtin_amdgcn_mfma_f32_16x16x32_f16(a1[0][1], xb1, c10, 0, 0, 0);
        c11 = __builtin_amdgcn_mfma_f32_16x16x32_f16(a1[1][1], xb1, c11, 0, 0, 0);
        c12 = __builtin_amdgcn_mfma_f32_16x16x32_f16(a1[2][1], xb1, c12, 0, 0, 0);

        f16x8 h0 = mk8(pkrelu(c10.x, c10.y), pkrelu(c10.z, c10.w),
                       pkrelu(c11.x, c11.y), pkrelu(c11.z, c11.w));
        f16x8 h1 = mk8(pkrelu(c12.x, c12.y), pkrelu(c12.z, c12.w), 0u, 0u);

        // fc2 (weights streamed from L1 per tile to cap register pressure)
        f32x4 c20 = {0.f, 0.f, 0.f, 0.f};
        f32x4 c21 = {0.f, 0.f, 0.f, 0.f};
        {
            f16x8 b0 = ldw_frag(w2p, l15,      64, 0, gq);
            f16x8 b1 = ldw_frag(w2p, 16 + l15, 64, 0, gq);
            c20 = __builtin_amdgcn_mfma_f32_16x16x32_f16(b0, h0, c20, 0, 0, 0);
            c21 = __builtin_amdgcn_mfma_f32_16x16x32_f16(b1, h0, c21, 0, 0, 0);
            b0 = ldw_frag(w2p, l15,      64, 32, gq);
            b1 = ldw_frag(w2p, 16 + l15, 64, 32, gq);
            c20 = __builtin_amdgcn_mfma_f32_16x16x32_f16(b0, h1, c20, 0, 0, 0);
            c21 = __builtin_amdgcn_mfma_f32_16x16x32_f16(b1, h1, c21, 0, 0, 0);
        }

        // fc3
        f16x8 h2 = mk8(pkrelu(c20.x, c20.y), pkrelu(c20.z, c20.w),
                       pkrelu(c21.x, c21.y), pkrelu(c21.z, c21.w));
        f32x4 c3 = {0.f, 0.f, 0.f, 0.f};
        {
            f16x8 a3 = ldw_frag(w3p, l15, 32, 0, gq);
            c3 = __builtin_amdgcn_mfma_f32_16x16x32_f16(a3, h2, c3, 0, 0, 0);
        }

        // fc4 delta + sigmoid
        float part = fmaxf(c3.x, 0.f) * w4v.x + fmaxf(c3.y, 0.f) * w4v.y +
                     fmaxf(c3.z, 0.f) * w4v.z + fmaxf(c3.w, 0.f) * w4v.w;
        part += __shfl_xor(part, 16);
        part += __shfl_xor(part, 32);
        float p1v = 1.f / (1.f + __expf(-part));
        if (gq == 0)
            out[r] = make_float2(1.f - p1v, p1v);
    }
}

extern "C" void kernel_launch(void* const* d_in, const int* in_sizes, int n_in,
                              void* d_out, int out_size, void* d_ws, size_t ws_size,
                              hipStream_t stream) {
    (void)in_sizes; (void)n_in; (void)ws_size; (void)out_size;
    char* ws = (char*)d_ws;
    prep_kernel<<<1, NTHR, 0, stream>>>(
        (const float*)d_in[2],  (const float*)d_in[3],
        (const float*)d_in[4],  (const float*)d_in[5],
        (const float*)d_in[6],
        (const float*)d_in[7],  (const float*)d_in[8],
        (const float*)d_in[9],  (const float*)d_in[10],
        (const float*)d_in[11], (const float*)d_in[12],
        (const float*)d_in[13], (const float*)d_in[14],
        (const float*)d_in[15], (const float*)d_in[16],
        (const float*)d_in[17], (const float*)d_in[18],
        (const float*)d_in[19], (const float*)d_in[20],
        (const float*)d_in[21], (const float*)d_in[22],
        (const float*)d_in[23], (const float*)d_in[24],
        (const float*)d_in[25], (const float*)d_in[26],
        (const float*)d_in[27], (const float*)d_in[28],
        (const float*)d_in[29], (const float*)d_in[30],
        ws);
    recovery_net_kernel<<<NBLOCKS, NTHR, 0, stream>>>(
        (const float*)d_in[0], (const int*)d_in[1], ws, (float2*)d_out);
}